// Round 15
// baseline (73.169 us; speedup 1.0000x reference)
//
#include <hip/hip_runtime.h>

// B=16, 12 in-ch, 128x128 imgs; conv1->64ch +pool -> 64x64; conv2->128ch (+PE);
// roi max -> out (16,32,128) f32.
//
// R15 = R14 + (a) k2f back to 1-row blocks (grid 64x16 -> 4 blocks/CU vs 2;
// k2f is latency-bound across its 4 serial phases) and (b) Aw2+rmask prep
// moved into k1's grid tail (R12's proven decode; hides under conv1).
// NO device-scope fences (R9/R13 lesson). Pipeline: kiop (imgT+Aw1) ;
// k1_mfma (1440 blk: conv1+relu+pool | Aw2 | rmask) ; k2f (conv2+relu+PE ->
// in-LDS mapped-u16 tile -> in-block roi-max -> partial[h]) ; k4_merge (64).

typedef __attribute__((ext_vector_type(8))) short short8;   // MFMA bf16 A/B frag
typedef __attribute__((ext_vector_type(4))) float f32x4;    // MFMA C/D frag
typedef __attribute__((ext_vector_type(4))) unsigned short us4;
typedef __attribute__((ext_vector_type(2))) unsigned short u16x2;
typedef unsigned short u16;
typedef unsigned int u32;

__device__ __forceinline__ u16 f2bf(float f) {  // RNE f32 -> bf16 bits
  u32 u = __builtin_bit_cast(u32, f);
  return (u16)((u + 0x7fffu + ((u >> 16) & 1u)) >> 16);
}
__device__ __forceinline__ u32 pkmaxu(u32 a, u32 b) {  // v_pk_max_u16
  u16x2 x = __builtin_bit_cast(u16x2, a), y = __builtin_bit_cast(u16x2, b);
  return __builtin_bit_cast(u32, __builtin_elementwise_max(x, y));
}
__device__ __forceinline__ u32 map2(u32 v) {  // monotone bf16->u16 map, x2
  u32 flip = ((v & 0x80008000u) >> 15) * 0xFFFFu;
  return v ^ (flip | 0x80008000u);
}
__device__ __forceinline__ float unmap1(u32 m) {  // mapped u16 -> f32
  u32 b = m ^ ((m & 0x8000u) ? 0x8000u : 0xFFFFu);
  return __builtin_bit_cast(float, b << 16);
}

namespace {

// ---------------- kiop: imgT (2048 blk) | Aw1 (40 blk) -----------------------
__global__ __launch_bounds__(256) void kiop(const float* __restrict__ img,
                                            u16* __restrict__ imgT,
                                            const float* __restrict__ w1,
                                            u16* __restrict__ Aw1) {
  __shared__ alignas(16) u16 ST[2048];
  const int bx = blockIdx.x;
  const int t = threadIdx.x;
  if (bx < 2048) {  // images f32 -> bf16 imgT [b][row][col][ci16], pad ci->0
    const int row = bx & 127, b = bx >> 7;
#pragma unroll
    for (int i = 0; i < 2; ++i) {
      const int e = i * 256 + t;
      ST[(e >> 2) * 16 + 12 + (e & 3)] = 0;
    }
#pragma unroll
    for (int i = 0; i < 6; ++i) {
      const int e = i * 256 + t;
      const int ci = e >> 7, col = e & 127;
      const float v = img[(((size_t)(b * 12 + ci)) << 14) + row * 128 + col];
      ST[col * 16 + ci] = f2bf(v);
    }
    __syncthreads();
    us4* dst = (us4*)(imgT + (((size_t)(b * 128 + row)) << 11));
#pragma unroll
    for (int i = 0; i < 2; ++i) {
      const int q = i * 256 + t;
      dst[q] = *(const us4*)&ST[q * 4];
    }
  } else {  // w1 -> Aw1 frags, K padded 108->160
    const int idx = (bx - 2048) * 256 + t;  // 0..10239
    const int j = idx & 7;
    const int lane = (idx >> 3) & 63;
    const int t3 = idx >> 9;
    const int ks = t3 % 5, cot = t3 / 5;
    const int m = lane & 15, g = lane >> 4;
    const int co = cot * 16 + m;
    const int k = ks * 32 + g * 8 + j;
    const int rc = k >> 4, cip = k & 15;
    const float v = (rc < 9 && cip < 12) ? w1[co * 108 + cip * 9 + rc] : 0.f;
    Aw1[idx] = f2bf(v);
  }
}

// ---------------- k1: [bx<1024] conv1+pool ; [1024,1312) Aw2 ; [1312,1440) rmask
__global__ __launch_bounds__(256) void k1_mfma(const u16* __restrict__ imgT,
                                               const u16* __restrict__ Aw1,
                                               const float* __restrict__ b1,
                                               u16* __restrict__ pooledT,
                                               const float* __restrict__ w2,
                                               u16* __restrict__ Aw2,
                                               const unsigned* __restrict__ rois,
                                               unsigned* __restrict__ rmask) {
  __shared__ alignas(16) u16 SIMG[8192];   // 16 KB, swizzled
  __shared__ alignas(16) u16 PT[64 * 68];  // pooled [pw][co]
  const int bx = blockIdx.x;
  const int t = threadIdx.x;

  if (bx >= 1024) {
    if (bx < 1312) {  // w2 -> Aw2 frags: k=32ks+g8+j -> (rc=k>>6, ci=k&63)
      const int idx = (bx - 1024) * 256 + t;  // 0..73727
      const int j = idx & 7;
      const int lane = (idx >> 3) & 63;
      const int t3 = idx >> 9;
      const int ks = t3 % 18, cot = t3 / 18;
      const int m = lane & 15, g = lane >> 4;
      const int co = cot * 16 + m;
      const int k = ks * 32 + g * 8 + j;
      const int rc = k >> 6, ci = k & 63;
      Aw2[idx] = f2bf(w2[co * 576 + ci * 9 + rc]);
    } else {  // rois[:,:,::2,::2] -> 32-bit object mask
      const int lane = t & 63;
      u32 ok = 1u;
#pragma unroll
      for (int i = 0; i < 4; ++i) {
        u32 v = rois[lane * 4 + i];
        ok &= ((v <= 1u) || (v == 0x3f800000u)) ? 1u : 0u;
      }
      const bool isWord = (__all((int)ok) != 0);
      const unsigned char* roisB = (const unsigned char*)rois;
      const int pi = (bx - 1312) * 256 + t;  // 0..32767
      const int b = pi >> 11;
      const int pp = pi & 2047;
      const int h = pp >> 5;
      const int wp = pp & 31;
      const size_t base = (size_t)b * 32 * 16384 + (size_t)(2 * h) * 128 + 4 * wp;
      u32 m0 = 0, m1 = 0;
#pragma unroll
      for (int o = 0; o < 32; ++o) {
        const size_t idx = base + (size_t)o * 16384;
        if (isWord) {
          const uint4 q = *(const uint4*)&rois[idx];
          m0 |= (u32)(q.x != 0u) << o;
          m1 |= (u32)(q.z != 0u) << o;
        } else {
          const u32 q = *(const u32*)&roisB[idx];
          m0 |= (u32)((q & 0xffu) != 0u) << o;
          m1 |= (u32)((q & 0xff0000u) != 0u) << o;
        }
      }
      *(uint2*)&rmask[b * 4096 + h * 64 + wp * 2] = make_uint2(m0, m1);
    }
    return;
  }

  const int h2 = bx & 63, b = bx >> 6;
  const int wv = t >> 6, l = t & 63;

#pragma unroll
  for (int i = 0; i < 4; ++i) {  // stage 4 rows x 4KB (swizzled store)
    const int q = i * 256 + t;
    const int sr = q >> 8, off = q & 255;
    const int irow = 2 * h2 - 1 + sr;
    short8 v = {0, 0, 0, 0, 0, 0, 0, 0};
    if ((unsigned)irow < 128u)
      v = *(const short8*)(imgT + (((size_t)(b * 128 + irow)) << 11) + off * 8);
    *(short8*)((char*)SIMG + ((q * 16) ^ (((q >> 3) & 1) << 4))) = v;
  }
  __syncthreads();

  const int m16 = l & 15, g = l >> 4;
  const int colhalf = wv >> 1, cotbase = (wv & 1) * 2;
  const int cipb = (g & 1) * 16;
  f32x4 acc[2][8];
#pragma unroll
  for (int ct = 0; ct < 2; ++ct)
#pragma unroll
    for (int pt = 0; pt < 8; ++pt) acc[ct][pt] = (f32x4){0.f, 0.f, 0.f, 0.f};

  const u16* awb = Aw1 + (size_t)l * 8;
  const short8 z8 = {0, 0, 0, 0, 0, 0, 0, 0};

#pragma unroll
  for (int ks = 0; ks < 5; ++ks) {
    short8 a0 = *(const short8*)(awb + (cotbase * 5 + ks) * 512);
    short8 a1 = *(const short8*)(awb + ((cotbase + 1) * 5 + ks) * 512);
    const bool pz = (ks == 4) && (g >= 2);  // zero-padded K slots
    const int rc = pz ? 0 : (2 * ks + (g >> 1));
    const int rr = (rc * 11) >> 5;  // rc/3
    const int cc = rc - rr * 3;     // rc%3
    const int d = m16 - 1 + cc;     // -1..16
    const int sb = (d < 0) ? 1 : ((d >> 2) & 1);
    const int base = rr * 4096 + d * 32 + colhalf * 2048 + (cipb ^ (sb << 4));
    const bool killLo = (cc == 0) && (m16 == 0) && (colhalf == 0);
    const bool killHi = (cc == 2) && (m16 == 15) && (colhalf == 1);
#pragma unroll
    for (int pt = 0; pt < 8; ++pt) {
      const int r01 = pt >> 2, ct2 = pt & 3;
      short8 bv = *(const short8*)((const char*)SIMG + base + r01 * 4096 + ct2 * 512);
      bool kill = pz;
      if (ct2 == 0) kill = kill || killLo;
      if (ct2 == 3) kill = kill || killHi;
      if (kill) bv = z8;
      acc[0][pt] = __builtin_amdgcn_mfma_f32_16x16x32_bf16(a0, bv, acc[0][pt], 0, 0, 0);
      acc[1][pt] = __builtin_amdgcn_mfma_f32_16x16x32_bf16(a1, bv, acc[1][pt], 0, 0, 0);
    }
  }

  // relu + 2x2 pool -> PT[pw][co]
#pragma unroll
  for (int ct = 0; ct < 2; ++ct) {
    const int cot = cotbase + ct;
#pragma unroll
    for (int r = 0; r < 4; ++r) {
      const int co = cot * 16 + g * 4 + r;
      const float bias = b1[co];
#pragma unroll
      for (int ct2 = 0; ct2 < 4; ++ct2) {
        float v0 = fmaxf(acc[ct][ct2][r] + bias, 0.f);
        float v1 = fmaxf(acc[ct][4 + ct2][r] + bias, 0.f);
        float vv = fmaxf(v0, v1);
        vv = fmaxf(vv, __shfl_xor(vv, 1, 64));
        if (!(m16 & 1)) {
          const int pw = colhalf * 32 + ct2 * 8 + (m16 >> 1);
          PT[pw * 68 + co] = f2bf(vv);
        }
      }
    }
  }
  __syncthreads();
  u16* dst = pooledT + (((size_t)(b * 64 + h2)) << 12);
#pragma unroll
  for (int i = 0; i < 4; ++i) {
    const int e = (i * 256 + t) * 4;
    const int pw = e >> 6, co = e & 63;
    *(us4*)(dst + e) = *(const us4*)&PT[pw * 68 + co];
  }
}

// ---------------- k2f: conv2 (1 row/block) + PE + in-block roi-max -----------
// grid (64,16) -> 4 blocks/CU (vs R14's 2): latency hiding across the 4
// serial phases. Stage rows h-1..h+1 (24 KB, T2 XOR swizzle); MFMA acc[2][4];
// epilogue -> mapped-u16 [64 pos][128 co] tile in reused SB (16 KB); scan with
// AND-zero diet (acc init map(+0)=0x8000). partial[h][b][o][co/2], 64 slabs.
__global__ __launch_bounds__(256) void k2f(const u16* __restrict__ pooledT,
                                           const u16* __restrict__ Aw,
                                           const float* __restrict__ b2,
                                           const float* __restrict__ dw,
                                           const float* __restrict__ db,
                                           const unsigned* __restrict__ rmask,
                                           u32* __restrict__ partial) {
  __shared__ alignas(16) char SB[25088];  // 24 KB staging (+pad) | out-tile
  __shared__ u32 MS[64];                  // 1 row of mask words
  const int h = blockIdx.x, b = blockIdx.y;
  const int t = threadIdx.x, wv = t >> 6, l = t & 63;

#pragma unroll
  for (int i = 0; i < 6; ++i) {  // stage rows h-1..h+1, T2 XOR swizzle
    const int chunk = i * 4 + wv;
    const int row = chunk >> 3;
    const int hin = h - 1 + row;
    short8 v = {0, 0, 0, 0, 0, 0, 0, 0};
    if ((unsigned)hin < 64u)
      v = *(const short8*)(pooledT + (((size_t)(b * 64 + hin)) << 12) +
                           ((chunk & 7) << 9) + l * 8);
    const int lin = chunk * 1024 + l * 16;
    *(short8*)(SB + (lin ^ (((lin >> 7) & 7) << 4))) = v;
  }
  if (t < 64) MS[t] = rmask[b * 4096 + h * 64 + t];
  __syncthreads();

  const int m16 = l & 15, g = l >> 4;
  const int kbyte = g * 16;
  f32x4 acc[2][4];
#pragma unroll
  for (int ct = 0; ct < 2; ++ct)
#pragma unroll
    for (int n = 0; n < 4; ++n) acc[ct][n] = (f32x4){0.f, 0.f, 0.f, 0.f};

  const u16* aw0 = Aw + (size_t)wv * 36 * 512 + l * 8;  // cot = 2wv
  const short8 z8 = {0, 0, 0, 0, 0, 0, 0, 0};

#pragma unroll
  for (int ks = 0; ks < 18; ++ks) {
    const int rc = ks >> 1, r = rc / 3, c = rc % 3;  // compile-time
    const int koff = r * 8192 + (ks & 1) * 64 + kbyte;
    short8 a0 = *(const short8*)(aw0 + ks * 512);
    short8 a1 = *(const short8*)(aw0 + (18 + ks) * 512);
    const int d = m16 + c - 1;  // -1..16
    const int base = (koff + d * 128) ^ ((d & 7) << 4);
    const bool edgeLo = (c == 0) && (m16 == 0);
    const bool edgeHi = (c == 2) && (m16 == 15);
#pragma unroll
    for (int n = 0; n < 4; ++n) {
      short8 bv = *(const short8*)(SB + base + n * 2048);
      if (c == 0 && n == 0) { if (edgeLo) bv = z8; }
      if (c == 2 && n == 3) { if (edgeHi) bv = z8; }
      acc[0][n] = __builtin_amdgcn_mfma_f32_16x16x32_bf16(a0, bv, acc[0][n], 0, 0, 0);
      acc[1][n] = __builtin_amdgcn_mfma_f32_16x16x32_bf16(a1, bv, acc[1][n], 0, 0, 0);
    }
  }

  __syncthreads();  // all waves done reading SB (WAR before tile overwrite)

  // epilogue: relu(acc+b2)+pe -> bf16 -> map -> SB[pos=w][co] (u32 stores)
  const float inv63 = 1.f / 63.f;
  const float gy = (float)h * inv63;
#pragma unroll
  for (int ct = 0; ct < 2; ++ct) {
    const int cot = wv * 2 + ct;
#pragma unroll
    for (int r2 = 0; r2 < 2; ++r2) {  // co pair
      const int co0 = cot * 16 + g * 4 + r2 * 2;
      const float bias0 = b2[co0], bias1 = b2[co0 + 1];
      const float pA0 = dw[co0 * 4 + 0] - dw[co0 * 4 + 2];
      const float pB0 = dw[co0 * 4 + 1] - dw[co0 * 4 + 3];
      const float pC0 = dw[co0 * 4 + 2] + dw[co0 * 4 + 3] + db[co0];
      const float pA1 = dw[co0 * 4 + 4] - dw[co0 * 4 + 6];
      const float pB1 = dw[co0 * 4 + 5] - dw[co0 * 4 + 7];
      const float pC1 = dw[co0 * 4 + 6] + dw[co0 * 4 + 7] + db[co0 + 1];
      const float pe00 = gy * pA0 + pC0;
      const float pe01 = gy * pA1 + pC1;
#pragma unroll
      for (int n4 = 0; n4 < 4; ++n4) {
        const int w = n4 * 16 + m16;
        const float gx = (float)w * inv63;
        const float v0 = fmaxf(acc[ct][n4][r2 * 2 + 0] + bias0, 0.f) + pe00 + gx * pB0;
        const float v1 = fmaxf(acc[ct][n4][r2 * 2 + 1] + bias1, 0.f) + pe01 + gx * pB1;
        const u32 pk = map2((u32)f2bf(v0) | ((u32)f2bf(v1) << 16));
        *(u32*)(SB + ((w * 256 + co0 * 2) ^ ((w & 7) << 4))) = pk;
      }
    }
  }
  __syncthreads();

  // in-block roi-max scan over 64 pos: thread = (og, coq) -> 4 o x 4 co cells.
  // acc init map(+0.0)=0x8000 -> masked-out contributes AND-zero (diet).
  const int og = t >> 5, coq = t & 31;
  u32 a0[4], a1[4];
#pragma unroll
  for (int r = 0; r < 4; ++r) { a0[r] = 0x80008000u; a1[r] = 0x80008000u; }
  for (int pos = 0; pos < 64; ++pos) {
    const u32 mw = MS[pos];  // wave-uniform -> broadcast
    const uint2 x = *(const uint2*)(SB + ((pos * 256 + coq * 8) ^ ((pos & 7) << 4)));
#pragma unroll
    for (int r = 0; r < 4; ++r) {
      const int o = og * 4 + r;
      const u32 am = (u32)((int)(mw << (31 - o)) >> 31);  // v_bfe_i32
      a0[r] = pkmaxu(a0[r], x.x & am);
      a1[r] = pkmaxu(a1[r], x.y & am);
    }
  }
  u32* pslab = partial + (size_t)h * 32768;
#pragma unroll
  for (int r = 0; r < 4; ++r) {  // static indices only (rule #20)
    const int o = og * 4 + r;
    *(uint2*)&pslab[((b * 32 + o) << 6) + coq * 2] = make_uint2(a0[r], a1[r]);
  }
}

// ---------------- k4: merge 64 h-partials (packed), unmap -> f32 out ---------
__global__ __launch_bounds__(256) void k4_merge(const u32* __restrict__ partial,
                                                float* __restrict__ out) {
  const int idx = blockIdx.x * 256 + threadIdx.x;  // 0..32767 u32 cells
  u32 v = partial[idx];
#pragma unroll
  for (int q = 1; q < 64; ++q) v = pkmaxu(v, partial[q * 32768 + idx]);
  float2 o2;
  o2.x = unmap1(v & 0xFFFFu);
  o2.y = unmap1(v >> 16);
  *(float2*)&out[idx * 2] = o2;
}

}  // namespace

extern "C" void kernel_launch(void* const* d_in, const int* in_sizes, int n_in,
                              void* d_out, int out_size, void* d_ws, size_t ws_size,
                              hipStream_t stream) {
  const float* images = (const float*)d_in[0];
  const unsigned* rois = (const unsigned*)d_in[1];
  const float* w1 = (const float*)d_in[2];
  const float* b1 = (const float*)d_in[3];
  const float* w2 = (const float*)d_in[4];
  const float* b2 = (const float*)d_in[5];
  const float* dw = (const float*)d_in[6];
  const float* db = (const float*)d_in[7];
  float* out = (float*)d_out;

  char* ws = (char*)d_ws;
  // rmask 256KB @0 ; pooledT 8MB @0x40000 ; Aw2 144KB @0x840000 ; Aw1 20KB
  // @0x864000 ; imgT 8MB @0x900000 (dead after k1) ; partial 8MB @0xD00000.
  unsigned* rmask = (unsigned*)(ws);
  u16* pooledT = (u16*)(ws + 0x40000);
  u16* Aw2 = (u16*)(ws + 0x840000);
  u16* Aw1 = (u16*)(ws + 0x864000);
  u16* imgT = (u16*)(ws + 0x900000);
  u32* partial = (u32*)(ws + 0xD00000);

  hipLaunchKernelGGL(kiop, dim3(2088), dim3(256), 0, stream,
                     images, imgT, w1, Aw1);
  hipLaunchKernelGGL(k1_mfma, dim3(1440), dim3(256), 0, stream,
                     imgT, Aw1, b1, pooledT, w2, Aw2, rois, rmask);
  hipLaunchKernelGGL(k2f, dim3(64, 16), dim3(256), 0, stream,
                     pooledT, Aw2, b2, dw, db, rmask, partial);
  hipLaunchKernelGGL(k4_merge, dim3(128), dim3(256), 0, stream, partial, out);
}

// Round 16
// 61.240 us; speedup vs baseline: 1.1948x; 1.1948x over previous
//
#include <hip/hip_runtime.h>

// B=16, 12 in-ch, 128x128 imgs; conv1->64ch +pool -> 64x64; conv2->128ch (+PE);
// roi max -> out (16,32,128) f32.
//
// R16 = R14 verbatim (best proven: 62.0us). R15's bundled changes (1-row k2f
// + prep-in-k1-tail) regressed +11us and are reverted. Structure: kiop
// (imgT+rmask+Aw2+Aw1) ; k1_mfma (conv1+relu+pool -> pooledT) ; k2f (conv2+
// relu+PE -> in-LDS mapped-u16 tile -> in-block roi-max -> partial[hp]) ;
// k4_merge. NO device-scope fences (R9/R13: 80-330us L2-flush storms).

typedef __attribute__((ext_vector_type(8))) short short8;   // MFMA bf16 A/B frag
typedef __attribute__((ext_vector_type(4))) float f32x4;    // MFMA C/D frag
typedef __attribute__((ext_vector_type(4))) unsigned short us4;
typedef __attribute__((ext_vector_type(2))) unsigned short u16x2;
typedef unsigned short u16;
typedef unsigned int u32;

__device__ __forceinline__ u16 f2bf(float f) {  // RNE f32 -> bf16 bits
  u32 u = __builtin_bit_cast(u32, f);
  return (u16)((u + 0x7fffu + ((u >> 16) & 1u)) >> 16);
}
__device__ __forceinline__ u32 pkmaxu(u32 a, u32 b) {  // v_pk_max_u16
  u16x2 x = __builtin_bit_cast(u16x2, a), y = __builtin_bit_cast(u16x2, b);
  return __builtin_bit_cast(u32, __builtin_elementwise_max(x, y));
}
__device__ __forceinline__ u32 map2(u32 v) {  // monotone bf16->u16 map, x2
  u32 flip = ((v & 0x80008000u) >> 15) * 0xFFFFu;
  return v ^ (flip | 0x80008000u);
}
__device__ __forceinline__ float unmap1(u32 m) {  // mapped u16 -> f32
  u32 b = m ^ ((m & 0x8000u) ? 0x8000u : 0xFFFFu);
  return __builtin_bit_cast(float, b << 16);
}

namespace {

// ---------------- kiop: imgT | rmask | Aw2 | Aw1 (fused prep) ----------------
__global__ __launch_bounds__(256) void kiop(const float* __restrict__ img,
                                            u16* __restrict__ imgT,
                                            const unsigned* __restrict__ rois,
                                            unsigned* __restrict__ rmask,
                                            const float* __restrict__ w2,
                                            u16* __restrict__ Aw2,
                                            const float* __restrict__ w1,
                                            u16* __restrict__ Aw1) {
  __shared__ alignas(16) u16 ST[2048];
  const int bx = blockIdx.x;
  const int t = threadIdx.x;
  if (bx < 2048) {  // images f32 -> bf16 imgT [b][row][col][ci16], pad ci->0
    const int row = bx & 127, b = bx >> 7;
#pragma unroll
    for (int i = 0; i < 2; ++i) {
      const int e = i * 256 + t;
      ST[(e >> 2) * 16 + 12 + (e & 3)] = 0;
    }
#pragma unroll
    for (int i = 0; i < 6; ++i) {
      const int e = i * 256 + t;
      const int ci = e >> 7, col = e & 127;
      const float v = img[(((size_t)(b * 12 + ci)) << 14) + row * 128 + col];
      ST[col * 16 + ci] = f2bf(v);
    }
    __syncthreads();
    us4* dst = (us4*)(imgT + (((size_t)(b * 128 + row)) << 11));
#pragma unroll
    for (int i = 0; i < 2; ++i) {
      const int q = i * 256 + t;
      dst[q] = *(const us4*)&ST[q * 4];
    }
  } else if (bx < 2176) {  // rois[:,:,::2,::2] -> 32-bit object mask
    const int lane = t & 63;
    u32 ok = 1u;
#pragma unroll
    for (int i = 0; i < 4; ++i) {
      u32 v = rois[lane * 4 + i];
      ok &= ((v <= 1u) || (v == 0x3f800000u)) ? 1u : 0u;
    }
    const bool isWord = (__all((int)ok) != 0);
    const unsigned char* roisB = (const unsigned char*)rois;
    const int pi = (bx - 2048) * 256 + t;  // 0..32767
    const int b = pi >> 11;
    const int pp = pi & 2047;
    const int h = pp >> 5;
    const int wp = pp & 31;
    const size_t base = (size_t)b * 32 * 16384 + (size_t)(2 * h) * 128 + 4 * wp;
    u32 m0 = 0, m1 = 0;
#pragma unroll
    for (int o = 0; o < 32; ++o) {
      const size_t idx = base + (size_t)o * 16384;
      if (isWord) {
        const uint4 q = *(const uint4*)&rois[idx];
        m0 |= (u32)(q.x != 0u) << o;
        m1 |= (u32)(q.z != 0u) << o;
      } else {
        const u32 q = *(const u32*)&roisB[idx];
        m0 |= (u32)((q & 0xffu) != 0u) << o;
        m1 |= (u32)((q & 0xff0000u) != 0u) << o;
      }
    }
    *(uint2*)&rmask[b * 4096 + h * 64 + wp * 2] = make_uint2(m0, m1);
  } else if (bx < 2464) {  // w2 -> Aw2 frags
    const int idx = (bx - 2176) * 256 + t;  // 0..73727
    const int j = idx & 7;
    const int lane = (idx >> 3) & 63;
    const int t3 = idx >> 9;
    const int ks = t3 % 18, cot = t3 / 18;
    const int m = lane & 15, g = lane >> 4;
    const int co = cot * 16 + m;
    const int k = ks * 32 + g * 8 + j;
    const int rc = k >> 6, ci = k & 63;
    Aw2[idx] = f2bf(w2[co * 576 + ci * 9 + rc]);
  } else {  // w1 -> Aw1 frags, K padded 108->160
    const int idx = (bx - 2464) * 256 + t;  // 0..10239
    const int j = idx & 7;
    const int lane = (idx >> 3) & 63;
    const int t3 = idx >> 9;
    const int ks = t3 % 5, cot = t3 / 5;
    const int m = lane & 15, g = lane >> 4;
    const int co = cot * 16 + m;
    const int k = ks * 32 + g * 8 + j;
    const int rc = k >> 4, cip = k & 15;
    const float v = (rc < 9 && cip < 12) ? w1[co * 108 + cip * 9 + rc] : 0.f;
    Aw1[idx] = f2bf(v);
  }
}

// ---------------- k1: conv1 (MFMA) + bias + relu + pool -> pooledT bf16 ------
__global__ __launch_bounds__(256) void k1_mfma(const u16* __restrict__ imgT,
                                               const u16* __restrict__ Aw1,
                                               const float* __restrict__ b1,
                                               u16* __restrict__ pooledT) {
  __shared__ alignas(16) u16 SIMG[8192];   // 16 KB, swizzled
  __shared__ alignas(16) u16 PT[64 * 68];  // pooled [pw][co]
  const int h2 = blockIdx.x, b = blockIdx.y;
  const int t = threadIdx.x, wv = t >> 6, l = t & 63;

#pragma unroll
  for (int i = 0; i < 4; ++i) {  // stage 4 rows x 4KB (swizzled store)
    const int q = i * 256 + t;
    const int sr = q >> 8, off = q & 255;
    const int irow = 2 * h2 - 1 + sr;
    short8 v = {0, 0, 0, 0, 0, 0, 0, 0};
    if ((unsigned)irow < 128u)
      v = *(const short8*)(imgT + (((size_t)(b * 128 + irow)) << 11) + off * 8);
    *(short8*)((char*)SIMG + ((q * 16) ^ (((q >> 3) & 1) << 4))) = v;
  }
  __syncthreads();

  const int m16 = l & 15, g = l >> 4;
  const int colhalf = wv >> 1, cotbase = (wv & 1) * 2;
  const int cipb = (g & 1) * 16;
  f32x4 acc[2][8];
#pragma unroll
  for (int ct = 0; ct < 2; ++ct)
#pragma unroll
    for (int pt = 0; pt < 8; ++pt) acc[ct][pt] = (f32x4){0.f, 0.f, 0.f, 0.f};

  const u16* awb = Aw1 + (size_t)l * 8;
  const short8 z8 = {0, 0, 0, 0, 0, 0, 0, 0};

#pragma unroll
  for (int ks = 0; ks < 5; ++ks) {
    short8 a0 = *(const short8*)(awb + (cotbase * 5 + ks) * 512);
    short8 a1 = *(const short8*)(awb + ((cotbase + 1) * 5 + ks) * 512);
    const bool pz = (ks == 4) && (g >= 2);  // zero-padded K slots
    const int rc = pz ? 0 : (2 * ks + (g >> 1));
    const int rr = (rc * 11) >> 5;  // rc/3
    const int cc = rc - rr * 3;     // rc%3
    const int d = m16 - 1 + cc;     // -1..16
    const int sb = (d < 0) ? 1 : ((d >> 2) & 1);
    const int base = rr * 4096 + d * 32 + colhalf * 2048 + (cipb ^ (sb << 4));
    const bool killLo = (cc == 0) && (m16 == 0) && (colhalf == 0);
    const bool killHi = (cc == 2) && (m16 == 15) && (colhalf == 1);
#pragma unroll
    for (int pt = 0; pt < 8; ++pt) {
      const int r01 = pt >> 2, ct2 = pt & 3;
      short8 bv = *(const short8*)((const char*)SIMG + base + r01 * 4096 + ct2 * 512);
      bool kill = pz;
      if (ct2 == 0) kill = kill || killLo;
      if (ct2 == 3) kill = kill || killHi;
      if (kill) bv = z8;
      acc[0][pt] = __builtin_amdgcn_mfma_f32_16x16x32_bf16(a0, bv, acc[0][pt], 0, 0, 0);
      acc[1][pt] = __builtin_amdgcn_mfma_f32_16x16x32_bf16(a1, bv, acc[1][pt], 0, 0, 0);
    }
  }

  // relu + 2x2 pool -> PT[pw][co]
#pragma unroll
  for (int ct = 0; ct < 2; ++ct) {
    const int cot = cotbase + ct;
#pragma unroll
    for (int r = 0; r < 4; ++r) {
      const int co = cot * 16 + g * 4 + r;
      const float bias = b1[co];
#pragma unroll
      for (int ct2 = 0; ct2 < 4; ++ct2) {
        float v0 = fmaxf(acc[ct][ct2][r] + bias, 0.f);
        float v1 = fmaxf(acc[ct][4 + ct2][r] + bias, 0.f);
        float vv = fmaxf(v0, v1);
        vv = fmaxf(vv, __shfl_xor(vv, 1, 64));
        if (!(m16 & 1)) {
          const int pw = colhalf * 32 + ct2 * 8 + (m16 >> 1);
          PT[pw * 68 + co] = f2bf(vv);
        }
      }
    }
  }
  __syncthreads();
  u16* dst = pooledT + (((size_t)(b * 64 + h2)) << 12);
#pragma unroll
  for (int i = 0; i < 4; ++i) {
    const int e = (i * 256 + t) * 4;
    const int pw = e >> 6, co = e & 63;
    *(us4*)(dst + e) = *(const us4*)&PT[pw * 68 + co];
  }
}

// ---------------- k2f: conv2 (MFMA) + bias + relu + PE + in-block roi-max ----
__global__ __launch_bounds__(256) void k2f(const u16* __restrict__ pooledT,
                                           const u16* __restrict__ Aw,
                                           const float* __restrict__ b2,
                                           const float* __restrict__ dw,
                                           const float* __restrict__ db,
                                           const unsigned* __restrict__ rmask,
                                           u32* __restrict__ partial) {
  __shared__ alignas(16) char SB[32768];  // stage 4 rows | then mapped out-tile
  __shared__ u32 MS[128];                 // 2 rows of mask words
  const int hp = blockIdx.x, b = blockIdx.y;
  const int t = threadIdx.x, wv = t >> 6, l = t & 63;

#pragma unroll
  for (int i = 0; i < 8; ++i) {  // stage rows 2hp-1..2hp+2, T2 XOR swizzle
    const int chunk = i * 4 + wv;
    const int row = chunk >> 3;
    const int hin = 2 * hp - 1 + row;
    short8 v = {0, 0, 0, 0, 0, 0, 0, 0};
    if ((unsigned)hin < 64u)
      v = *(const short8*)(pooledT + (((size_t)(b * 64 + hin)) << 12) +
                           ((chunk & 7) << 9) + l * 8);
    const int lin = chunk * 1024 + l * 16;
    *(short8*)(SB + (lin ^ (((lin >> 7) & 7) << 4))) = v;
  }
  if (t < 128) MS[t] = rmask[b * 4096 + hp * 128 + t];
  __syncthreads();

  const int m16 = l & 15, g = l >> 4;
  const int kbyte = g * 16;
  f32x4 acc[2][8];  // [ct][n], n = orw*4 + n4
#pragma unroll
  for (int ct = 0; ct < 2; ++ct)
#pragma unroll
    for (int n = 0; n < 8; ++n) acc[ct][n] = (f32x4){0.f, 0.f, 0.f, 0.f};

  const u16* aw0 = Aw + (size_t)wv * 36 * 512 + l * 8;  // cot = 2wv
  const short8 z8 = {0, 0, 0, 0, 0, 0, 0, 0};

#pragma unroll
  for (int ks = 0; ks < 18; ++ks) {
    const int rc = ks >> 1, r = rc / 3, c = rc % 3;  // compile-time
    const int koff = r * 8192 + (ks & 1) * 64 + kbyte;
    short8 a0 = *(const short8*)(aw0 + ks * 512);
    short8 a1 = *(const short8*)(aw0 + (18 + ks) * 512);
    const int d = m16 + c - 1;  // -1..16
    const int base = (koff + d * 128) ^ ((d & 7) << 4);
    const bool edgeLo = (c == 0) && (m16 == 0);
    const bool edgeHi = (c == 2) && (m16 == 15);
#pragma unroll
    for (int n = 0; n < 8; ++n) {
      const int orw = n >> 2, n4 = n & 3;
      short8 bv = *(const short8*)(SB + base + orw * 8192 + n4 * 2048);
      if (c == 0 && n4 == 0) { if (edgeLo) bv = z8; }
      if (c == 2 && n4 == 3) { if (edgeHi) bv = z8; }
      acc[0][n] = __builtin_amdgcn_mfma_f32_16x16x32_bf16(a0, bv, acc[0][n], 0, 0, 0);
      acc[1][n] = __builtin_amdgcn_mfma_f32_16x16x32_bf16(a1, bv, acc[1][n], 0, 0, 0);
    }
  }

  __syncthreads();  // all waves done reading SB (WAR before tile overwrite)

  // epilogue: relu(acc+b2)+pe -> bf16 -> map -> SB[pos][co] (u32 pair stores)
  const float inv63 = 1.f / 63.f;
#pragma unroll
  for (int ct = 0; ct < 2; ++ct) {
    const int cot = wv * 2 + ct;
#pragma unroll
    for (int r2 = 0; r2 < 2; ++r2) {  // co pair (r = 2*r2 + j)
      const int co0 = cot * 16 + g * 4 + r2 * 2;
      const float bias0 = b2[co0], bias1 = b2[co0 + 1];
      const float pA0 = dw[co0 * 4 + 0] - dw[co0 * 4 + 2];
      const float pB0 = dw[co0 * 4 + 1] - dw[co0 * 4 + 3];
      const float pC0 = dw[co0 * 4 + 2] + dw[co0 * 4 + 3] + db[co0];
      const float pA1 = dw[co0 * 4 + 4] - dw[co0 * 4 + 6];
      const float pB1 = dw[co0 * 4 + 5] - dw[co0 * 4 + 7];
      const float pC1 = dw[co0 * 4 + 6] + dw[co0 * 4 + 7] + db[co0 + 1];
#pragma unroll
      for (int orw = 0; orw < 2; ++orw) {
        const float gy = (float)(2 * hp + orw) * inv63;
        const float pe00 = gy * pA0 + pC0;
        const float pe01 = gy * pA1 + pC1;
#pragma unroll
        for (int n4 = 0; n4 < 4; ++n4) {
          const int w = n4 * 16 + m16;
          const int pos = orw * 64 + w;
          const float gx = (float)w * inv63;
          const float v0 = fmaxf(acc[ct][orw * 4 + n4][r2 * 2 + 0] + bias0, 0.f)
                           + pe00 + gx * pB0;
          const float v1 = fmaxf(acc[ct][orw * 4 + n4][r2 * 2 + 1] + bias1, 0.f)
                           + pe01 + gx * pB1;
          const u32 pk = map2((u32)f2bf(v0) | ((u32)f2bf(v1) << 16));
          *(u32*)(SB + ((pos * 256 + co0 * 2) ^ ((pos & 7) << 4))) = pk;
        }
      }
    }
  }
  __syncthreads();

  // in-block roi-max scan: thread = (og 0..7, coq 0..31) -> 4 o x 4 co cells.
  // Scan diet: acc init = map(+0.0)=0x8000 per half -> masked-out contributes
  // AND-zero (mapped-domain minimum, never beats the 0x8000 floor). Matches
  // reference's x*r (0.0 candidate at every zero bit); differs only if ALL
  // 4096 bits of an (b,o) mask are 1 AND every value < 0 (P ~ 2^-4096).
  const int og = t >> 5, coq = t & 31;
  u32 a0[4], a1[4];  // [r]; a0 = co {4coq,4coq+1}, a1 = co {4coq+2,4coq+3}
#pragma unroll
  for (int r = 0; r < 4; ++r) { a0[r] = 0x80008000u; a1[r] = 0x80008000u; }
  for (int pos = 0; pos < 128; ++pos) {
    const u32 mw = MS[pos];  // wave-uniform -> broadcast
    const uint2 x = *(const uint2*)(SB + ((pos * 256 + coq * 8) ^ ((pos & 7) << 4)));
#pragma unroll
    for (int r = 0; r < 4; ++r) {
      const int o = og * 4 + r;
      const u32 am = (u32)((int)(mw << (31 - o)) >> 31);  // v_bfe_i32
      a0[r] = pkmaxu(a0[r], x.x & am);
      a1[r] = pkmaxu(a1[r], x.y & am);
    }
  }
  u32* pslab = partial + (size_t)hp * 32768;
#pragma unroll
  for (int r = 0; r < 4; ++r) {  // static indices only (rule #20)
    const int o = og * 4 + r;
    *(uint2*)&pslab[((b * 32 + o) << 6) + coq * 2] = make_uint2(a0[r], a1[r]);
  }
}

// ---------------- k4: merge 32 hp-partials (packed), unmap -> f32 out --------
__global__ __launch_bounds__(256) void k4_merge(const u32* __restrict__ partial,
                                                float* __restrict__ out) {
  const int idx = blockIdx.x * 256 + threadIdx.x;  // 0..32767 u32 cells
  u32 v = partial[idx];
#pragma unroll
  for (int q = 1; q < 32; ++q) v = pkmaxu(v, partial[q * 32768 + idx]);
  float2 o2;
  o2.x = unmap1(v & 0xFFFFu);
  o2.y = unmap1(v >> 16);
  *(float2*)&out[idx * 2] = o2;
}

}  // namespace

extern "C" void kernel_launch(void* const* d_in, const int* in_sizes, int n_in,
                              void* d_out, int out_size, void* d_ws, size_t ws_size,
                              hipStream_t stream) {
  const float* images = (const float*)d_in[0];
  const unsigned* rois = (const unsigned*)d_in[1];
  const float* w1 = (const float*)d_in[2];
  const float* b1 = (const float*)d_in[3];
  const float* w2 = (const float*)d_in[4];
  const float* b2 = (const float*)d_in[5];
  const float* dw = (const float*)d_in[6];
  const float* db = (const float*)d_in[7];
  float* out = (float*)d_out;

  char* ws = (char*)d_ws;
  // rmask 256KB @0 ; pooledT 8MB @0x40000 ; Aw2 144KB @0x840000 ; Aw1 20KB
  // @0x864000 ; imgT 8MB @0x900000 (dead after k1) ; partial 4MB @0xD00000.
  unsigned* rmask = (unsigned*)(ws);
  u16* pooledT = (u16*)(ws + 0x40000);
  u16* Aw2 = (u16*)(ws + 0x840000);
  u16* Aw1 = (u16*)(ws + 0x864000);
  u16* imgT = (u16*)(ws + 0x900000);
  u32* partial = (u32*)(ws + 0xD00000);

  hipLaunchKernelGGL(kiop, dim3(2504), dim3(256), 0, stream,
                     images, imgT, rois, rmask, w2, Aw2, w1, Aw1);
  hipLaunchKernelGGL(k1_mfma, dim3(64, 16), dim3(256), 0, stream, imgT, Aw1, b1, pooledT);
  hipLaunchKernelGGL(k2f, dim3(32, 16), dim3(256), 0, stream,
                     pooledT, Aw2, b2, dw, db, rmask, partial);
  hipLaunchKernelGGL(k4_merge, dim3(128), dim3(256), 0, stream, partial, out);
}